// Round 4
// baseline (1810.352 us; speedup 1.0000x reference)
//
#include <hip/hip_runtime.h>
#include <hip/hip_bf16.h>
#include <math.h>

#define D_MODEL 512
#define N_HEADS 8
#define D_HEAD  64
#define D_FF    2048
#define SEQ     512
#define BATCH   8
#define ROWS    (BATCH * SEQ)          /* 4096 */
#define PRED_LEN 96
#define KLEN_MASKED (SEQ - PRED_LEN)   /* 416 */
#define LN_EPS  1e-5f

typedef float  f32x4 __attribute__((ext_vector_type(4)));
typedef short  s16x8 __attribute__((ext_vector_type(8)));

__device__ __forceinline__ float bf2f(ushort u) {
    union { unsigned int i; float f; } c; c.i = ((unsigned int)u) << 16; return c.f;
}
__device__ __forceinline__ ushort f2bf(float v) {
    __hip_bfloat16 h = __float2bfloat16(v);
    return *(ushort*)&h;
}
__device__ __forceinline__ void gl_lds16(const void* g, void* lds) {
    __builtin_amdgcn_global_load_lds(
        (const __attribute__((address_space(1))) unsigned int*)g,
        (__attribute__((address_space(3))) unsigned int*)lds, 16, 0, 0);
}

/* ============ bf16 MFMA GEMM: C = A @ Bt^T + bias, opt relu =================
 * A [M,K] bf16 row stride lda;  Bt [N,K] bf16 k-contig;  C [M,N] bf16.
 * BM=128, BK=32, 4 waves 2x2.  If VT!=null, blocks with n0>=vcol0 write
 * transposed per-head V: vt[(b*8+h)*64+d][p] instead of C.
 */
template<int BN>
__global__ __launch_bounds__(256) void gemm_mfma(
    const ushort* __restrict__ A, int lda,
    const ushort* __restrict__ Bt, int ldb,
    ushort* __restrict__ C, int ldc,
    int K, const float* __restrict__ bias, int relu,
    ushort* __restrict__ VT, int vcol0)
{
    constexpr int NW = BN / 32;
    __shared__ __attribute__((aligned(16))) ushort As[128 * 32];
    __shared__ __attribute__((aligned(16))) ushort Bs[BN * 32];
    const int tid = threadIdx.x;
    const int w = tid >> 6, lane = tid & 63;
    const int l16 = lane & 15, quad = lane >> 4;
    const int m0 = blockIdx.y * 128, n0 = blockIdx.x * BN;
    const ushort* Ab = A + (size_t)m0 * lda;
    const ushort* Bb = Bt + (size_t)n0 * ldb;
    const int wm = (w >> 1) * 64, wn = (w & 1) * (BN / 2);

    f32x4 acc[4][NW];
    #pragma unroll
    for (int i = 0; i < 4; ++i)
        #pragma unroll
        for (int j = 0; j < NW; ++j) acc[i][j] = (f32x4)0.f;

    for (int k0 = 0; k0 < K; k0 += 32) {
        #pragma unroll
        for (int t = 0; t < 2; ++t) {
            int c = (t * 4 + w) * 64 + lane;
            gl_lds16(Ab + (size_t)(c >> 2) * lda + k0 + (c & 3) * 8,
                     (void*)(As + (size_t)(t * 4 + w) * 512));
        }
        #pragma unroll
        for (int t = 0; t < BN / 64; ++t) {
            int c = (t * 4 + w) * 64 + lane;
            gl_lds16(Bb + (size_t)(c >> 2) * ldb + k0 + (c & 3) * 8,
                     (void*)(Bs + (size_t)(t * 4 + w) * 512));
        }
        __syncthreads();
        s16x8 af[4];
        #pragma unroll
        for (int i = 0; i < 4; ++i)
            af[i] = *(const s16x8*)(As + (size_t)(wm + i * 16 + l16) * 32 + quad * 8);
        #pragma unroll
        for (int j = 0; j < NW; ++j) {
            s16x8 bfr = *(const s16x8*)(Bs + (size_t)(wn + j * 16 + l16) * 32 + quad * 8);
            #pragma unroll
            for (int i = 0; i < 4; ++i)
                acc[i][j] = __builtin_amdgcn_mfma_f32_16x16x32_bf16(af[i], bfr, acc[i][j], 0, 0, 0);
        }
        __syncthreads();
    }
    const bool isv = (VT != nullptr) && (n0 >= vcol0);
    if (isv) {
        /* transposed V write: 4 contiguous bf16 (one 8B store) per (i,j) */
        #pragma unroll
        for (int i = 0; i < 4; ++i) {
            int mrow = m0 + wm + i * 16 + quad * 4;
            int b = mrow >> 9, pbase = mrow & 511;
            #pragma unroll
            for (int j = 0; j < NW; ++j) {
                int cv = n0 + wn + j * 16 + l16 - vcol0;   /* 0..511 */
                int h = cv >> 6, d = cv & 63;
                union { ushort u[4]; uint2 v; } pk;
                #pragma unroll
                for (int r = 0; r < 4; ++r) pk.u[r] = f2bf(acc[i][j][r]);
                *(uint2*)(VT + ((size_t)((b * 8 + h) * 64 + d) * 512 + pbase)) = pk.v;
            }
        }
    } else {
        #pragma unroll
        for (int i = 0; i < 4; ++i) {
            #pragma unroll
            for (int j = 0; j < NW; ++j) {
                int col = n0 + wn + j * 16 + l16;
                float bv = bias ? bias[col] : 0.f;
                #pragma unroll
                for (int r = 0; r < 4; ++r) {
                    float v = acc[i][j][r] + bv;
                    if (relu) v = fmaxf(v, 0.f);
                    C[(size_t)(m0 + wm + i * 16 + quad * 4 + r) * ldc + col] = f2bf(v);
                }
            }
        }
    }
}

/* ============ fused GEMM + bias + residual-add + LayerNorm ==================
 * out = LN(A @ Bt^T + bias + resid32) * gamma + beta   (row width N=512)
 * A [4096,K] bf16 lda;  Bt [512,K];  resid32/out32 fp32 [4096,512]; outb bf16.
 * BM=16 rows/block, 4 waves x 128 cols, grid = 256 blocks.
 */
__global__ __launch_bounds__(256) void gemm_ln(
    const ushort* __restrict__ A, int lda,
    const ushort* __restrict__ Bt,
    const float* __restrict__ bias,
    const float* __restrict__ resid32,
    const float* __restrict__ gamma, const float* __restrict__ beta,
    float* __restrict__ out32, ushort* __restrict__ outb, int K)
{
    __shared__ __attribute__((aligned(16))) ushort As[16 * 32];
    __shared__ __attribute__((aligned(16))) ushort Bs[512 * 32];
    __shared__ float ps[4][16];
    const int tid = threadIdx.x;
    const int w = tid >> 6, lane = tid & 63;
    const int l16 = lane & 15, quad = lane >> 4;
    const int m0 = blockIdx.x * 16;
    const ushort* Ab = A + (size_t)m0 * lda;

    f32x4 acc[8];
    #pragma unroll
    for (int j = 0; j < 8; ++j) acc[j] = (f32x4)0.f;

    for (int k0 = 0; k0 < K; k0 += 32) {
        if (w == 0)
            gl_lds16(Ab + (size_t)(lane >> 2) * lda + k0 + (lane & 3) * 8, (void*)As);
        #pragma unroll
        for (int it = 0; it < 8; ++it) {
            int c = it * 256 + tid;
            gl_lds16(Bt + (size_t)(c >> 2) * K + k0 + (c & 3) * 8,
                     (void*)(Bs + (size_t)(it * 4 + w) * 512));
        }
        __syncthreads();
        s16x8 af = *(const s16x8*)(As + (size_t)l16 * 32 + quad * 8);
        #pragma unroll
        for (int j = 0; j < 8; ++j) {
            s16x8 bfr = *(const s16x8*)(Bs + (size_t)(w * 128 + j * 16 + l16) * 32 + quad * 8);
            acc[j] = __builtin_amdgcn_mfma_f32_16x16x32_bf16(af, bfr, acc[j], 0, 0, 0);
        }
        __syncthreads();
    }

    /* cols this lane owns: w*128 + j*16 + l16; rows: quad*4+r */
    float bv[8], gv[8], btv[8];
    #pragma unroll
    for (int j = 0; j < 8; ++j) {
        int col = w * 128 + j * 16 + l16;
        bv[j]  = bias ? bias[col] : 0.f;
        gv[j]  = gamma[col];
        btv[j] = beta[col];
    }
    float mu[4], rs[4];
    #pragma unroll
    for (int r = 0; r < 4; ++r) {
        int row = quad * 4 + r;
        float s = 0.f;
        #pragma unroll
        for (int j = 0; j < 8; ++j) {
            int col = w * 128 + j * 16 + l16;
            float v = acc[j][r] + bv[j] + resid32[(size_t)(m0 + row) * 512 + col];
            acc[j][r] = v;
            s += v;
        }
        s += __shfl_xor(s, 1); s += __shfl_xor(s, 2);
        s += __shfl_xor(s, 4); s += __shfl_xor(s, 8);
        if (l16 == 0) ps[w][row] = s;
    }
    __syncthreads();
    #pragma unroll
    for (int r = 0; r < 4; ++r) {
        int row = quad * 4 + r;
        mu[r] = (ps[0][row] + ps[1][row] + ps[2][row] + ps[3][row]) * (1.f / 512.f);
    }
    __syncthreads();
    #pragma unroll
    for (int r = 0; r < 4; ++r) {
        int row = quad * 4 + r;
        float s = 0.f;
        #pragma unroll
        for (int j = 0; j < 8; ++j) {
            float d = acc[j][r] - mu[r];
            s += d * d;
        }
        s += __shfl_xor(s, 1); s += __shfl_xor(s, 2);
        s += __shfl_xor(s, 4); s += __shfl_xor(s, 8);
        if (l16 == 0) ps[w][row] = s;
    }
    __syncthreads();
    #pragma unroll
    for (int r = 0; r < 4; ++r) {
        int row = quad * 4 + r;
        float var = (ps[0][row] + ps[1][row] + ps[2][row] + ps[3][row]) * (1.f / 512.f);
        rs[r] = rsqrtf(var + LN_EPS);
    }
    #pragma unroll
    for (int r = 0; r < 4; ++r) {
        int row = m0 + quad * 4 + r;
        #pragma unroll
        for (int j = 0; j < 8; ++j) {
            int col = w * 128 + j * 16 + l16;
            float y = (acc[j][r] - mu[r]) * rs[r] * gv[j] + btv[j];
            out32[(size_t)row * 512 + col] = y;
            outb[(size_t)row * 512 + col]  = f2bf(y);
        }
    }
}

/* ============ flash attention: O = softmax(Q K^T / 8, klen) V =============== */
__global__ __launch_bounds__(256) void flash_attn(
    const ushort* __restrict__ Q, int ldq,
    const ushort* __restrict__ K, int ldk,
    const ushort* __restrict__ Vt,
    ushort* __restrict__ O, int ldo, int klen)
{
    __shared__ __attribute__((aligned(16))) ushort KVs[8192];
    __shared__ __attribute__((aligned(16))) ushort Es[4][2048];
    const int tid = threadIdx.x, w = tid >> 6, lane = tid & 63;
    const int l16 = lane & 15, quad = lane >> 4;
    const int bh = blockIdx.y, b = bh >> 3, h = bh & 7;
    const int q0 = blockIdx.x * 64;

    const ushort* Qb = Q + (size_t)(b * SEQ) * ldq + h * D_HEAD;
    const ushort* Kb = K + (size_t)(b * SEQ) * ldk + h * D_HEAD;

    s16x8 af0, af1;
    {
        const ushort* qr = Qb + (size_t)(q0 + w * 16 + l16) * ldq + quad * 8;
        af0 = *(const s16x8*)(qr);
        af1 = *(const s16x8*)(qr + 32);
    }

    f32x4 sc[32];

    #pragma unroll
    for (int kc = 0; kc < 4; ++kc) {
        #pragma unroll
        for (int it = 0; it < 4; ++it) {
            int cc = (it * 4 + w) * 64 + lane;
            int row = cc >> 3;
            int dch = (cc & 7) ^ (row & 7);
            gl_lds16(Kb + (size_t)(kc * 128 + row) * ldk + dch * 8,
                     (void*)(KVs + (size_t)(it * 4 + w) * 512));
        }
        __syncthreads();
        #pragma unroll
        for (int kt = 0; kt < 8; ++kt) {
            int r0 = kt * 16 + l16;
            s16x8 b0 = *(const s16x8*)(KVs + r0 * 64 + ((quad)     ^ (r0 & 7)) * 8);
            s16x8 b1 = *(const s16x8*)(KVs + r0 * 64 + ((4 + quad) ^ (r0 & 7)) * 8);
            f32x4 a = __builtin_amdgcn_mfma_f32_16x16x32_bf16(af0, b0, (f32x4)0.f, 0, 0, 0);
            sc[kc * 8 + kt] = __builtin_amdgcn_mfma_f32_16x16x32_bf16(af1, b1, a, 0, 0, 0);
        }
        __syncthreads();
    }

    float inv[4];
    #pragma unroll
    for (int r = 0; r < 4; ++r) {
        float m = -1e30f;
        #pragma unroll
        for (int j = 0; j < 32; ++j) {
            bool valid = (j * 16 + l16) < klen;
            m = valid ? fmaxf(m, sc[j][r]) : m;
        }
        m = fmaxf(m, __shfl_xor(m, 1));
        m = fmaxf(m, __shfl_xor(m, 2));
        m = fmaxf(m, __shfl_xor(m, 4));
        m = fmaxf(m, __shfl_xor(m, 8));
        float ssum = 0.f;
        #pragma unroll
        for (int j = 0; j < 32; ++j) {
            bool valid = (j * 16 + l16) < klen;
            float e = valid ? __expf((sc[j][r] - m) * 0.125f) : 0.f;
            sc[j][r] = e;
            ssum += e;
        }
        ssum += __shfl_xor(ssum, 1);
        ssum += __shfl_xor(ssum, 2);
        ssum += __shfl_xor(ssum, 4);
        ssum += __shfl_xor(ssum, 8);
        inv[r] = 1.f / ssum;
    }

    f32x4 oacc[4];
    #pragma unroll
    for (int jd = 0; jd < 4; ++jd) oacc[jd] = (f32x4)0.f;
    const ushort* Vb = Vt + (size_t)bh * (D_HEAD * SEQ);
    #pragma unroll
    for (int kc = 0; kc < 4; ++kc) {
        #pragma unroll
        for (int it = 0; it < 4; ++it) {
            int cc = (it * 4 + w) * 64 + lane;
            int d = cc >> 4;
            int kch = (cc & 15) ^ (d & 15);
            gl_lds16(Vb + (size_t)d * SEQ + kc * 128 + kch * 8,
                     (void*)(KVs + (size_t)(it * 4 + w) * 512));
        }
        #pragma unroll
        for (int j = 0; j < 8; ++j) {
            int lcj = j * 2 + (l16 >> 3);
            #pragma unroll
            for (int r = 0; r < 4; ++r) {
                int m = quad * 4 + r;
                Es[w][m * 128 + (lcj ^ m) * 8 + (l16 & 7)] = f2bf(sc[kc * 8 + j][r]);
            }
        }
        __syncthreads();
        #pragma unroll
        for (int ks = 0; ks < 4; ++ks) {
            int lc = ks * 4 + quad;
            s16x8 ea = *(const s16x8*)(&Es[w][l16 * 128 + (lc ^ l16) * 8]);
            #pragma unroll
            for (int jd = 0; jd < 4; ++jd) {
                int row = jd * 16 + l16;
                s16x8 vb = *(const s16x8*)(KVs + row * 128 + (lc ^ l16) * 8);
                oacc[jd] = __builtin_amdgcn_mfma_f32_16x16x32_bf16(ea, vb, oacc[jd], 0, 0, 0);
            }
        }
        __syncthreads();
    }

    ushort* Ob = O + (size_t)(b * SEQ) * ldo + h * D_HEAD;
    #pragma unroll
    for (int jd = 0; jd < 4; ++jd)
        #pragma unroll
        for (int r = 0; r < 4; ++r)
            Ob[(size_t)(q0 + w * 16 + quad * 4 + r) * ldo + jd * 16 + l16] =
                f2bf(oacc[jd][r] * inv[r]);
}

/* ============ batched weight repacks ============ */
struct AttnPtrs { const float* p[48]; };
struct FfPtrs   { const float* p[16]; };

__global__ __launch_bounds__(256) void repack_attn(AttnPtrs L, ushort* __restrict__ out)
{
    int z = blockIdx.z;
    const float* in = L.p[z];
    ushort* o = out + (size_t)z * 262144;
    __shared__ float t[32][33];
    int n0 = blockIdx.x * 32, k0 = blockIdx.y * 32;
    int tx = threadIdx.x & 31, ty = threadIdx.x >> 5;
    #pragma unroll
    for (int r = 0; r < 4; ++r)
        t[ty + r * 8][tx] = in[(size_t)(k0 + ty + r * 8) * 512 + n0 + tx];
    __syncthreads();
    #pragma unroll
    for (int r = 0; r < 4; ++r)
        o[(size_t)(n0 + ty + r * 8) * 512 + k0 + tx] = f2bf(t[tx][ty + r * 8]);
}

__global__ __launch_bounds__(256) void repack_ff(FfPtrs L, ushort* __restrict__ out)
{
    int z = blockIdx.y;
    int Kd = (z < 8) ? 512 : 2048, Nd = (z < 8) ? 2048 : 512;
    const float* in = L.p[z];
    ushort* o = out + (size_t)z * (512 * 2048);
    int t = blockIdx.x;
    int tn = Nd / 32;
    int n0 = (t % tn) * 32, k0 = (t / tn) * 32;
    __shared__ float ts[32][33];
    int tx = threadIdx.x & 31, ty = threadIdx.x >> 5;
    #pragma unroll
    for (int r = 0; r < 4; ++r)
        ts[ty + r * 8][tx] = in[(size_t)(k0 + ty + r * 8) * Nd + n0 + tx];
    __syncthreads();
    #pragma unroll
    for (int r = 0; r < 4; ++r)
        o[(size_t)(n0 + ty + r * 8) * Kd + k0 + tx] = f2bf(ts[tx][ty + r * 8]);
}

/* ============ input projection ============ */
__global__ __launch_bounds__(256) void input_proj(
    const float* __restrict__ x, const float* __restrict__ w,
    const float* __restrict__ bias, const float* __restrict__ pos,
    float* __restrict__ out32, ushort* __restrict__ outb, int in_size)
{
    int idx = blockIdx.x * 256 + threadIdx.x;
    int col = idx & (D_MODEL - 1);
    int row = idx >> 9;
    int l   = row & (SEQ - 1);
    const float* xr = x + (size_t)row * in_size;
    float acc = bias[col] + pos[(size_t)l * D_MODEL + col];
    for (int t = 0; t < in_size; ++t) acc += xr[t] * w[(size_t)t * D_MODEL + col];
    out32[idx] = acc;
    outb[idx]  = f2bf(acc);
}

/* ============ final projection ============ */
__global__ __launch_bounds__(256) void final_proj(
    const float* __restrict__ X, const float* __restrict__ W,
    const float* __restrict__ b, float* __restrict__ out)
{
    int idx = blockIdx.x * 256 + threadIdx.x;
    int row = idx >> 3, c = idx & 7;
    const float* xr = X + (size_t)row * D_MODEL;
    float acc = b[c];
    for (int t = 0; t < D_MODEL; ++t) acc += xr[t] * W[t * 8 + c];
    out[idx] = acc;
}

/* ============================ host orchestration ============================ */
extern "C" void kernel_launch(void* const* d_in, const int* in_sizes, int n_in,
                              void* d_out, int out_size, void* d_ws, size_t ws_size,
                              hipStream_t stream)
{
    const float* src         = (const float*)d_in[0];
    const float* tgt         = (const float*)d_in[1];
    const float* src_pos     = (const float*)d_in[2];
    const float* tgt_pos     = (const float*)d_in[3];
    const float* src_lin_w   = (const float*)d_in[4];
    const float* src_lin_b   = (const float*)d_in[5];
    const float* tgt_lin_w   = (const float*)d_in[6];
    const float* tgt_lin_b   = (const float*)d_in[7];
    const float* enc_wq      = (const float*)d_in[8];
    const float* enc_wk      = (const float*)d_in[9];
    const float* enc_wv      = (const float*)d_in[10];
    const float* enc_wo      = (const float*)d_in[11];
    const float* enc_ff1_w   = (const float*)d_in[12];
    const float* enc_ff1_b   = (const float*)d_in[13];
    const float* enc_ff2_w   = (const float*)d_in[14];
    const float* enc_ff2_b   = (const float*)d_in[15];
    const float* enc_ln1_g   = (const float*)d_in[16];
    const float* enc_ln1_b   = (const float*)d_in[17];
    const float* enc_ln2_g   = (const float*)d_in[18];
    const float* enc_ln2_b   = (const float*)d_in[19];
    const float* dec_sa_wq   = (const float*)d_in[20];
    const float* dec_sa_wk   = (const float*)d_in[21];
    const float* dec_sa_wv   = (const float*)d_in[22];
    const float* dec_sa_wo   = (const float*)d_in[23];
    const float* dec_ca_wq   = (const float*)d_in[24];
    const float* dec_ca_wk   = (const float*)d_in[25];
    const float* dec_ca_wv   = (const float*)d_in[26];
    const float* dec_ca_wo   = (const float*)d_in[27];
    const float* dec_ff1_w   = (const float*)d_in[28];
    const float* dec_ff1_b   = (const float*)d_in[29];
    const float* dec_ff2_w   = (const float*)d_in[30];
    const float* dec_ff2_b   = (const float*)d_in[31];
    const float* dec_ln1_g   = (const float*)d_in[32];
    const float* dec_ln1_b   = (const float*)d_in[33];
    const float* dec_ln2_g   = (const float*)d_in[34];
    const float* dec_ln2_b   = (const float*)d_in[35];
    const float* dec_ln3_g   = (const float*)d_in[36];
    const float* dec_ln3_b   = (const float*)d_in[37];
    const float* proj_w      = (const float*)d_in[38];
    const float* proj_b      = (const float*)d_in[39];

    /* ---- workspace carve ---- */
    char* p = (char*)d_ws;
    auto carve = [&](size_t bytes) { char* r = p; p += (bytes + 255) & ~(size_t)255; return r; };
    ushort* enc_xb = (ushort*)carve((size_t)ROWS * D_MODEL * 2);
    ushort* dec_xb = (ushort*)carve((size_t)ROWS * D_MODEL * 2);
    float*  enc_x32= (float*) carve((size_t)ROWS * D_MODEL * 4);
    float*  dec_x32= (float*) carve((size_t)ROWS * D_MODEL * 4);
    ushort* qkvb   = (ushort*)carve((size_t)ROWS * 1536 * 2);
    ushort* qb     = (ushort*)carve((size_t)ROWS * D_MODEL * 2);
    ushort* kvb    = (ushort*)carve((size_t)ROWS * 1024 * 2);
    ushort* ctxb   = (ushort*)carve((size_t)ROWS * D_MODEL * 2);
    ushort* ffhb   = (ushort*)carve((size_t)ROWS * D_FF * 2);
    ushort* vt     = (ushort*)carve((size_t)64 * D_HEAD * SEQ * 2);
    ushort* wa     = (ushort*)carve((size_t)48 * 262144 * 2);
    ushort* wf     = (ushort*)carve((size_t)16 * 1048576 * 2);

    const dim3 blk(256);

    /* ---- weight repack (2 launches) ---- */
    {
        AttnPtrs A;
        for (int i = 0; i < 4; ++i) {
            const size_t o = (size_t)i * 262144;
            A.p[i * 3 + 0] = enc_wq + o;  A.p[i * 3 + 1] = enc_wk + o;  A.p[i * 3 + 2] = enc_wv + o;
            A.p[12 + i] = enc_wo + o;
            A.p[16 + i * 3 + 0] = dec_sa_wq + o; A.p[16 + i * 3 + 1] = dec_sa_wk + o;
            A.p[16 + i * 3 + 2] = dec_sa_wv + o;
            A.p[28 + i] = dec_sa_wo + o;
            A.p[32 + i * 2 + 0] = dec_ca_wk + o; A.p[32 + i * 2 + 1] = dec_ca_wv + o;
            A.p[40 + i] = dec_ca_wq + o;
            A.p[44 + i] = dec_ca_wo + o;
        }
        repack_attn<<<dim3(16, 16, 48), blk, 0, stream>>>(A, wa);
        FfPtrs F;
        for (int i = 0; i < 4; ++i) {
            F.p[0 + i]  = enc_ff1_w + (size_t)i * 1048576;
            F.p[4 + i]  = dec_ff1_w + (size_t)i * 1048576;
            F.p[8 + i]  = enc_ff2_w + (size_t)i * 1048576;
            F.p[12 + i] = dec_ff2_w + (size_t)i * 1048576;
        }
        repack_ff<<<dim3(1024, 16), blk, 0, stream>>>(F, wf);
    }

    auto g128 = [&](const ushort* A, int lda, const ushort* Bt, int ldb,
                    ushort* C, int ldc, int M, int N, int K,
                    const float* bias, int relu, ushort* VT, int vcol0) {
        gemm_mfma<128><<<dim3(N / 128, M / 128), blk, 0, stream>>>(
            A, lda, Bt, ldb, C, ldc, K, bias, relu, VT, vcol0);
    };
    auto g64 = [&](const ushort* A, int lda, const ushort* Bt, int ldb,
                   ushort* C, int ldc, int M, int N, int K,
                   const float* bias, int relu) {
        gemm_mfma<64><<<dim3(N / 64, M / 128), blk, 0, stream>>>(
            A, lda, Bt, ldb, C, ldc, K, bias, relu, nullptr, 0);
    };
    auto gln = [&](const ushort* A, int lda, const ushort* Bt, const float* bias,
                   const float* resid, const float* g_, const float* b_,
                   float* o32, ushort* ob, int K) {
        gemm_ln<<<dim3(ROWS / 16), blk, 0, stream>>>(A, lda, Bt, bias, resid,
                                                     g_, b_, o32, ob, K);
    };

    /* input projections */
    input_proj<<<ROWS * D_MODEL / 256, blk, 0, stream>>>(src, src_lin_w, src_lin_b,
                                                         src_pos, enc_x32, enc_xb, 16);
    input_proj<<<ROWS * D_MODEL / 256, blk, 0, stream>>>(tgt, tgt_lin_w, tgt_lin_b,
                                                         tgt_pos, dec_x32, dec_xb, 8);

    /* ===================== encoder ===================== */
    for (int i = 0; i < 4; ++i) {
        g128(enc_xb, 512, wa + (size_t)(i * 3) * 262144, 512, qkvb, 1536,
             ROWS, 1536, 512, nullptr, 0, vt, 1024);
        flash_attn<<<dim3(8, 64), blk, 0, stream>>>(qkvb, 1536, qkvb + 512, 1536, vt,
                                                    ctxb, D_MODEL, SEQ);
        gln(ctxb, 512, wa + (size_t)(12 + i) * 262144, nullptr, enc_x32,
            enc_ln1_g + i * 512, enc_ln1_b + i * 512, enc_x32, enc_xb, 512);
        g128(enc_xb, 512, wf + (size_t)i * 1048576, 512, ffhb, 2048,
             ROWS, 2048, 512, enc_ff1_b + i * 2048, 1, nullptr, 0);
        gln(ffhb, 2048, wf + (size_t)(8 + i) * 1048576, enc_ff2_b + i * 512, enc_x32,
            enc_ln2_g + i * 512, enc_ln2_b + i * 512, enc_x32, enc_xb, 2048);
    }

    /* ===================== decoder ===================== */
    for (int i = 0; i < 4; ++i) {
        /* masked self-attention */
        g128(dec_xb, 512, wa + (size_t)(16 + i * 3) * 262144, 512, qkvb, 1536,
             ROWS, 1536, 512, nullptr, 0, vt, 1024);
        flash_attn<<<dim3(8, 64), blk, 0, stream>>>(qkvb, 1536, qkvb + 512, 1536, vt,
                                                    ctxb, D_MODEL, KLEN_MASKED);
        gln(ctxb, 512, wa + (size_t)(28 + i) * 262144, nullptr, dec_x32,
            dec_ln1_g + i * 512, dec_ln1_b + i * 512, dec_x32, dec_xb, 512);
        /* cross-attention */
        g64(dec_xb, 512, wa + (size_t)(40 + i) * 262144, 512, qb, 512,
            ROWS, 512, 512, nullptr, 0);
        g128(enc_xb, 512, wa + (size_t)(32 + i * 2) * 262144, 512, kvb, 1024,
             ROWS, 1024, 512, nullptr, 0, vt, 512);
        flash_attn<<<dim3(8, 64), blk, 0, stream>>>(qb, 512, kvb, 1024, vt,
                                                    ctxb, D_MODEL, SEQ);
        gln(ctxb, 512, wa + (size_t)(44 + i) * 262144, nullptr, dec_x32,
            dec_ln2_g + i * 512, dec_ln2_b + i * 512, dec_x32, dec_xb, 512);
        /* feed-forward */
        g128(dec_xb, 512, wf + (size_t)(4 + i) * 1048576, 512, ffhb, 2048,
             ROWS, 2048, 512, dec_ff1_b + i * 2048, 1, nullptr, 0);
        gln(ffhb, 2048, wf + (size_t)(12 + i) * 1048576, dec_ff2_b + i * 512, dec_x32,
            dec_ln3_g + i * 512, dec_ln3_b + i * 512, dec_x32, dec_xb, 2048);
    }

    /* final projection */
    final_proj<<<ROWS * 8 / 256, blk, 0, stream>>>(dec_x32, proj_w, proj_b, (float*)d_out);
}

// Round 5
// 1554.736 us; speedup vs baseline: 1.1644x; 1.1644x over previous
//
#include <hip/hip_runtime.h>
#include <hip/hip_bf16.h>
#include <math.h>

#define D_MODEL 512
#define N_HEADS 8
#define D_HEAD  64
#define D_FF    2048
#define SEQ     512
#define BATCH   8
#define ROWS    (BATCH * SEQ)          /* 4096 */
#define PRED_LEN 96
#define KLEN_MASKED (SEQ - PRED_LEN)   /* 416 */
#define LN_EPS  1e-5f

typedef float  f32x4 __attribute__((ext_vector_type(4)));
typedef short  s16x8 __attribute__((ext_vector_type(8)));

__device__ __forceinline__ float bf2f(ushort u) {
    union { unsigned int i; float f; } c; c.i = ((unsigned int)u) << 16; return c.f;
}
__device__ __forceinline__ ushort f2bf(float v) {
    __hip_bfloat16 h = __float2bfloat16(v);
    return *(ushort*)&h;
}
__device__ __forceinline__ void gl_lds16(const void* g, void* lds) {
    __builtin_amdgcn_global_load_lds(
        (const __attribute__((address_space(1))) unsigned int*)g,
        (__attribute__((address_space(3))) unsigned int*)lds, 16, 0, 0);
}

/* ============ GEMM descriptor + shared MFMA body ============================
 * C = A[M,K] @ Bt[N,K]^T + bias (opt relu). BM=128, BK=32, 4 waves 2x2.
 * If VT != null, blocks with n0 >= vcol0 write transposed per-head V:
 * vt[(b*8+h)*64+d][p] instead of C (validated round 4).
 */
struct GDesc {
    const ushort* A; int lda;
    const ushort* Bt; int ldb;
    ushort* C; int ldc;
    int N; int K;
    const float* bias; int relu;
    ushort* VT; int vcol0;
};

template<int BN>
__device__ __forceinline__ void gemm_body(const GDesc& d)
{
    constexpr int NW = BN / 32;
    __shared__ __attribute__((aligned(16))) ushort As[128 * 32];
    __shared__ __attribute__((aligned(16))) ushort Bs[BN * 32];
    const int tid = threadIdx.x;
    const int w = tid >> 6, lane = tid & 63;
    const int l16 = lane & 15, quad = lane >> 4;
    const int m0 = blockIdx.y * 128, n0 = blockIdx.x * BN;
    const ushort* Ab = d.A + (size_t)m0 * d.lda;
    const ushort* Bb = d.Bt + (size_t)n0 * d.ldb;
    const int wm = (w >> 1) * 64, wn = (w & 1) * (BN / 2);
    const int K = d.K;

    f32x4 acc[4][NW];
    #pragma unroll
    for (int i = 0; i < 4; ++i)
        #pragma unroll
        for (int j = 0; j < NW; ++j) acc[i][j] = (f32x4)0.f;

    for (int k0 = 0; k0 < K; k0 += 32) {
        #pragma unroll
        for (int t = 0; t < 2; ++t) {
            int c = (t * 4 + w) * 64 + lane;
            gl_lds16(Ab + (size_t)(c >> 2) * d.lda + k0 + (c & 3) * 8,
                     (void*)(As + (size_t)(t * 4 + w) * 512));
        }
        #pragma unroll
        for (int t = 0; t < BN / 64; ++t) {
            int c = (t * 4 + w) * 64 + lane;
            gl_lds16(Bb + (size_t)(c >> 2) * d.ldb + k0 + (c & 3) * 8,
                     (void*)(Bs + (size_t)(t * 4 + w) * 512));
        }
        __syncthreads();
        s16x8 af[4];
        #pragma unroll
        for (int i = 0; i < 4; ++i)
            af[i] = *(const s16x8*)(As + (size_t)(wm + i * 16 + l16) * 32 + quad * 8);
        #pragma unroll
        for (int j = 0; j < NW; ++j) {
            s16x8 bfr = *(const s16x8*)(Bs + (size_t)(wn + j * 16 + l16) * 32 + quad * 8);
            #pragma unroll
            for (int i = 0; i < 4; ++i)
                acc[i][j] = __builtin_amdgcn_mfma_f32_16x16x32_bf16(af[i], bfr, acc[i][j], 0, 0, 0);
        }
        __syncthreads();
    }
    const bool isv = (d.VT != nullptr) && (n0 >= d.vcol0);
    if (isv) {
        #pragma unroll
        for (int i = 0; i < 4; ++i) {
            int mrow = m0 + wm + i * 16 + quad * 4;
            int b = mrow >> 9, pbase = mrow & 511;
            #pragma unroll
            for (int j = 0; j < NW; ++j) {
                int cv = n0 + wn + j * 16 + l16 - d.vcol0;   /* 0..511 */
                int h = cv >> 6, dd = cv & 63;
                union { ushort u[4]; uint2 v; } pk;
                #pragma unroll
                for (int r = 0; r < 4; ++r) pk.u[r] = f2bf(acc[i][j][r]);
                *(uint2*)(d.VT + ((size_t)((b * 8 + h) * 64 + dd) * 512 + pbase)) = pk.v;
            }
        }
    } else {
        #pragma unroll
        for (int i = 0; i < 4; ++i) {
            #pragma unroll
            for (int j = 0; j < NW; ++j) {
                int col = n0 + wn + j * 16 + l16;
                float bv = d.bias ? d.bias[col] : 0.f;
                #pragma unroll
                for (int r = 0; r < 4; ++r) {
                    float v = acc[i][j][r] + bv;
                    if (d.relu) v = fmaxf(v, 0.f);
                    d.C[(size_t)(m0 + wm + i * 16 + quad * 4 + r) * d.ldc + col] = f2bf(v);
                }
            }
        }
    }
}

template<int BN>
__global__ __launch_bounds__(256) void gemm_one(GDesc d)
{
    if ((int)(blockIdx.x * BN) < d.N) gemm_body<BN>(d);
}

__global__ __launch_bounds__(256) void gemm_two(GDesc d0, GDesc d1)
{
    const GDesc& d = blockIdx.z ? d1 : d0;
    if ((int)(blockIdx.x * 128) < d.N) gemm_body<128>(d);
}

/* ============ flash attention: O = softmax(Q K^T / 8, klen) V =============== */
__global__ __launch_bounds__(256) void flash_attn(
    const ushort* __restrict__ Q, int ldq,
    const ushort* __restrict__ K, int ldk,
    const ushort* __restrict__ Vt,
    ushort* __restrict__ O, int ldo, int klen)
{
    __shared__ __attribute__((aligned(16))) ushort KVs[8192];
    __shared__ __attribute__((aligned(16))) ushort Es[4][2048];
    const int tid = threadIdx.x, w = tid >> 6, lane = tid & 63;
    const int l16 = lane & 15, quad = lane >> 4;
    const int bh = blockIdx.y, b = bh >> 3, h = bh & 7;
    const int q0 = blockIdx.x * 64;

    const ushort* Qb = Q + (size_t)(b * SEQ) * ldq + h * D_HEAD;
    const ushort* Kb = K + (size_t)(b * SEQ) * ldk + h * D_HEAD;

    s16x8 af0, af1;
    {
        const ushort* qr = Qb + (size_t)(q0 + w * 16 + l16) * ldq + quad * 8;
        af0 = *(const s16x8*)(qr);
        af1 = *(const s16x8*)(qr + 32);
    }

    f32x4 sc[32];

    #pragma unroll
    for (int kc = 0; kc < 4; ++kc) {
        #pragma unroll
        for (int it = 0; it < 4; ++it) {
            int cc = (it * 4 + w) * 64 + lane;
            int row = cc >> 3;
            int dch = (cc & 7) ^ (row & 7);
            gl_lds16(Kb + (size_t)(kc * 128 + row) * ldk + dch * 8,
                     (void*)(KVs + (size_t)(it * 4 + w) * 512));
        }
        __syncthreads();
        #pragma unroll
        for (int kt = 0; kt < 8; ++kt) {
            int r0 = kt * 16 + l16;
            s16x8 b0 = *(const s16x8*)(KVs + r0 * 64 + ((quad)     ^ (r0 & 7)) * 8);
            s16x8 b1 = *(const s16x8*)(KVs + r0 * 64 + ((4 + quad) ^ (r0 & 7)) * 8);
            f32x4 a = __builtin_amdgcn_mfma_f32_16x16x32_bf16(af0, b0, (f32x4)0.f, 0, 0, 0);
            sc[kc * 8 + kt] = __builtin_amdgcn_mfma_f32_16x16x32_bf16(af1, b1, a, 0, 0, 0);
        }
        __syncthreads();
    }

    float inv[4];
    #pragma unroll
    for (int r = 0; r < 4; ++r) {
        float m = -1e30f;
        #pragma unroll
        for (int j = 0; j < 32; ++j) {
            bool valid = (j * 16 + l16) < klen;
            m = valid ? fmaxf(m, sc[j][r]) : m;
        }
        m = fmaxf(m, __shfl_xor(m, 1));
        m = fmaxf(m, __shfl_xor(m, 2));
        m = fmaxf(m, __shfl_xor(m, 4));
        m = fmaxf(m, __shfl_xor(m, 8));
        float ssum = 0.f;
        #pragma unroll
        for (int j = 0; j < 32; ++j) {
            bool valid = (j * 16 + l16) < klen;
            float e = valid ? __expf((sc[j][r] - m) * 0.125f) : 0.f;
            sc[j][r] = e;
            ssum += e;
        }
        ssum += __shfl_xor(ssum, 1);
        ssum += __shfl_xor(ssum, 2);
        ssum += __shfl_xor(ssum, 4);
        ssum += __shfl_xor(ssum, 8);
        inv[r] = 1.f / ssum;
    }

    f32x4 oacc[4];
    #pragma unroll
    for (int jd = 0; jd < 4; ++jd) oacc[jd] = (f32x4)0.f;
    const ushort* Vb = Vt + (size_t)bh * (D_HEAD * SEQ);
    #pragma unroll
    for (int kc = 0; kc < 4; ++kc) {
        #pragma unroll
        for (int it = 0; it < 4; ++it) {
            int cc = (it * 4 + w) * 64 + lane;
            int d = cc >> 4;
            int kch = (cc & 15) ^ (d & 15);
            gl_lds16(Vb + (size_t)d * SEQ + kc * 128 + kch * 8,
                     (void*)(KVs + (size_t)(it * 4 + w) * 512));
        }
        #pragma unroll
        for (int j = 0; j < 8; ++j) {
            int lcj = j * 2 + (l16 >> 3);
            #pragma unroll
            for (int r = 0; r < 4; ++r) {
                int m = quad * 4 + r;
                Es[w][m * 128 + (lcj ^ m) * 8 + (l16 & 7)] = f2bf(sc[kc * 8 + j][r]);
            }
        }
        __syncthreads();
        #pragma unroll
        for (int ks = 0; ks < 4; ++ks) {
            int lc = ks * 4 + quad;
            s16x8 ea = *(const s16x8*)(&Es[w][l16 * 128 + (lc ^ l16) * 8]);
            #pragma unroll
            for (int jd = 0; jd < 4; ++jd) {
                int row = jd * 16 + l16;
                s16x8 vb = *(const s16x8*)(KVs + row * 128 + (lc ^ l16) * 8);
                oacc[jd] = __builtin_amdgcn_mfma_f32_16x16x32_bf16(ea, vb, oacc[jd], 0, 0, 0);
            }
        }
        __syncthreads();
    }

    ushort* Ob = O + (size_t)(b * SEQ) * ldo + h * D_HEAD;
    #pragma unroll
    for (int jd = 0; jd < 4; ++jd)
        #pragma unroll
        for (int r = 0; r < 4; ++r)
            Ob[(size_t)(q0 + w * 16 + quad * 4 + r) * ldo + jd * 16 + l16] =
                f2bf(oacc[jd][r] * inv[r]);
}

/* ============ batched weight repacks ============ */
struct AttnPtrs { const float* p[48]; };
struct FfPtrs   { const float* p[16]; };

__global__ __launch_bounds__(256) void repack_attn(AttnPtrs L, ushort* __restrict__ out)
{
    int z = blockIdx.z;
    const float* in = L.p[z];
    ushort* o = out + (size_t)z * 262144;
    __shared__ float t[32][33];
    int n0 = blockIdx.x * 32, k0 = blockIdx.y * 32;
    int tx = threadIdx.x & 31, ty = threadIdx.x >> 5;
    #pragma unroll
    for (int r = 0; r < 4; ++r)
        t[ty + r * 8][tx] = in[(size_t)(k0 + ty + r * 8) * 512 + n0 + tx];
    __syncthreads();
    #pragma unroll
    for (int r = 0; r < 4; ++r)
        o[(size_t)(n0 + ty + r * 8) * 512 + k0 + tx] = f2bf(t[tx][ty + r * 8]);
}

__global__ __launch_bounds__(256) void repack_ff(FfPtrs L, ushort* __restrict__ out)
{
    int z = blockIdx.y;
    int Kd = (z < 8) ? 512 : 2048, Nd = (z < 8) ? 2048 : 512;
    const float* in = L.p[z];
    ushort* o = out + (size_t)z * (512 * 2048);
    int t = blockIdx.x;
    int tn = Nd / 32;
    int n0 = (t % tn) * 32, k0 = (t / tn) * 32;
    __shared__ float ts[32][33];
    int tx = threadIdx.x & 31, ty = threadIdx.x >> 5;
    #pragma unroll
    for (int r = 0; r < 4; ++r)
        ts[ty + r * 8][tx] = in[(size_t)(k0 + ty + r * 8) * Nd + n0 + tx];
    __syncthreads();
    #pragma unroll
    for (int r = 0; r < 4; ++r)
        o[(size_t)(n0 + ty + r * 8) * Kd + k0 + tx] = f2bf(ts[tx][ty + r * 8]);
}

/* ============ dual input projection (z=0 src, z=1 tgt) ============ */
__global__ __launch_bounds__(256) void input_proj2(
    const float* __restrict__ x0, const float* __restrict__ w0,
    const float* __restrict__ b0, const float* __restrict__ p0,
    float* __restrict__ o0_32, ushort* __restrict__ o0_b, int in0,
    const float* __restrict__ x1, const float* __restrict__ w1,
    const float* __restrict__ b1, const float* __restrict__ p1,
    float* __restrict__ o1_32, ushort* __restrict__ o1_b, int in1)
{
    const int z = blockIdx.y;
    const float* x = z ? x1 : x0;  const float* w = z ? w1 : w0;
    const float* bias = z ? b1 : b0; const float* pos = z ? p1 : p0;
    float* out32 = z ? o1_32 : o0_32; ushort* outb = z ? o1_b : o0_b;
    int in_size = z ? in1 : in0;
    int idx = blockIdx.x * 256 + threadIdx.x;
    int col = idx & (D_MODEL - 1);
    int row = idx >> 9;
    int l   = row & (SEQ - 1);
    const float* xr = x + (size_t)row * in_size;
    float acc = bias[col] + pos[(size_t)l * D_MODEL + col];
    for (int t = 0; t < in_size; ++t) acc += xr[t] * w[(size_t)t * D_MODEL + col];
    out32[idx] = acc;
    outb[idx]  = f2bf(acc);
}

/* ============ residual add + LayerNorm (fp32 carrier) ============ */
__global__ __launch_bounds__(256) void add_ln(
    const ushort* __restrict__ a, const float* __restrict__ x,
    const float* __restrict__ g, const float* __restrict__ b,
    float* __restrict__ out32, ushort* __restrict__ outb)
{
    int row = blockIdx.x;
    int tid = threadIdx.x;
    const ushort* ar = a + (size_t)row * D_MODEL;
    const float*  xr = x + (size_t)row * D_MODEL;
    float v0 = bf2f(ar[tid]) + xr[tid];
    float v1 = bf2f(ar[tid + 256]) + xr[tid + 256];
    __shared__ float red[256];
    red[tid] = v0 + v1;
    __syncthreads();
    for (int s = 128; s; s >>= 1) {
        if (tid < s) red[tid] += red[tid + s];
        __syncthreads();
    }
    float mu = red[0] * (1.f / D_MODEL);
    __syncthreads();
    float d0 = v0 - mu, d1 = v1 - mu;
    red[tid] = d0 * d0 + d1 * d1;
    __syncthreads();
    for (int s = 128; s; s >>= 1) {
        if (tid < s) red[tid] += red[tid + s];
        __syncthreads();
    }
    float rs = rsqrtf(red[0] * (1.f / D_MODEL) + LN_EPS);
    float y0 = d0 * rs * g[tid]       + b[tid];
    float y1 = d1 * rs * g[tid + 256] + b[tid + 256];
    size_t base = (size_t)row * D_MODEL;
    out32[base + tid] = y0;        out32[base + tid + 256] = y1;
    outb[base + tid]  = f2bf(y0);  outb[base + tid + 256]  = f2bf(y1);
}

/* ============ final projection ============ */
__global__ __launch_bounds__(256) void final_proj(
    const float* __restrict__ X, const float* __restrict__ W,
    const float* __restrict__ b, float* __restrict__ out)
{
    int idx = blockIdx.x * 256 + threadIdx.x;
    int row = idx >> 3, c = idx & 7;
    const float* xr = X + (size_t)row * D_MODEL;
    float acc = b[c];
    for (int t = 0; t < D_MODEL; ++t) acc += xr[t] * W[t * 8 + c];
    out[idx] = acc;
}

/* ============================ host orchestration ============================ */
extern "C" void kernel_launch(void* const* d_in, const int* in_sizes, int n_in,
                              void* d_out, int out_size, void* d_ws, size_t ws_size,
                              hipStream_t stream)
{
    const float* src         = (const float*)d_in[0];
    const float* tgt         = (const float*)d_in[1];
    const float* src_pos     = (const float*)d_in[2];
    const float* tgt_pos     = (const float*)d_in[3];
    const float* src_lin_w   = (const float*)d_in[4];
    const float* src_lin_b   = (const float*)d_in[5];
    const float* tgt_lin_w   = (const float*)d_in[6];
    const float* tgt_lin_b   = (const float*)d_in[7];
    const float* enc_wq      = (const float*)d_in[8];
    const float* enc_wk      = (const float*)d_in[9];
    const float* enc_wv      = (const float*)d_in[10];
    const float* enc_wo      = (const float*)d_in[11];
    const float* enc_ff1_w   = (const float*)d_in[12];
    const float* enc_ff1_b   = (const float*)d_in[13];
    const float* enc_ff2_w   = (const float*)d_in[14];
    const float* enc_ff2_b   = (const float*)d_in[15];
    const float* enc_ln1_g   = (const float*)d_in[16];
    const float* enc_ln1_b   = (const float*)d_in[17];
    const float* enc_ln2_g   = (const float*)d_in[18];
    const float* enc_ln2_b   = (const float*)d_in[19];
    const float* dec_sa_wq   = (const float*)d_in[20];
    const float* dec_sa_wk   = (const float*)d_in[21];
    const float* dec_sa_wv   = (const float*)d_in[22];
    const float* dec_sa_wo   = (const float*)d_in[23];
    const float* dec_ca_wq   = (const float*)d_in[24];
    const float* dec_ca_wk   = (const float*)d_in[25];
    const float* dec_ca_wv   = (const float*)d_in[26];
    const float* dec_ca_wo   = (const float*)d_in[27];
    const float* dec_ff1_w   = (const float*)d_in[28];
    const float* dec_ff1_b   = (const float*)d_in[29];
    const float* dec_ff2_w   = (const float*)d_in[30];
    const float* dec_ff2_b   = (const float*)d_in[31];
    const float* dec_ln1_g   = (const float*)d_in[32];
    const float* dec_ln1_b   = (const float*)d_in[33];
    const float* dec_ln2_g   = (const float*)d_in[34];
    const float* dec_ln2_b   = (const float*)d_in[35];
    const float* dec_ln3_g   = (const float*)d_in[36];
    const float* dec_ln3_b   = (const float*)d_in[37];
    const float* proj_w      = (const float*)d_in[38];
    const float* proj_b      = (const float*)d_in[39];

    /* ---- workspace carve ---- */
    char* p = (char*)d_ws;
    auto carve = [&](size_t bytes) { char* r = p; p += (bytes + 255) & ~(size_t)255; return r; };
    ushort* enc_xb = (ushort*)carve((size_t)ROWS * D_MODEL * 2);
    ushort* dec_xb = (ushort*)carve((size_t)ROWS * D_MODEL * 2);
    float*  enc_x32= (float*) carve((size_t)ROWS * D_MODEL * 4);
    float*  dec_x32= (float*) carve((size_t)ROWS * D_MODEL * 4);
    ushort* qkvb   = (ushort*)carve((size_t)ROWS * 1536 * 2);
    ushort* qb     = (ushort*)carve((size_t)ROWS * D_MODEL * 2);
    ushort* kvb    = (ushort*)carve((size_t)ROWS * 1024 * 2);
    ushort* ctxb   = (ushort*)carve((size_t)ROWS * D_MODEL * 2);
    ushort* attnb  = (ushort*)carve((size_t)ROWS * D_MODEL * 2);
    ushort* ffhb   = (ushort*)carve((size_t)ROWS * D_FF * 2);
    ushort* vt     = (ushort*)carve((size_t)64 * D_HEAD * SEQ * 2);
    ushort* wa     = (ushort*)carve((size_t)48 * 262144 * 2);
    ushort* wf     = (ushort*)carve((size_t)16 * 1048576 * 2);

    const dim3 blk(256);

    /* ---- weight repack (2 launches) ---- */
    {
        AttnPtrs A;
        for (int i = 0; i < 4; ++i) {
            const size_t o = (size_t)i * 262144;
            A.p[i * 3 + 0] = enc_wq + o;  A.p[i * 3 + 1] = enc_wk + o;  A.p[i * 3 + 2] = enc_wv + o;
            A.p[12 + i] = enc_wo + o;
            A.p[16 + i * 3 + 0] = dec_sa_wq + o; A.p[16 + i * 3 + 1] = dec_sa_wk + o;
            A.p[16 + i * 3 + 2] = dec_sa_wv + o;
            A.p[28 + i] = dec_sa_wo + o;
            A.p[32 + i * 2 + 0] = dec_ca_wk + o; A.p[32 + i * 2 + 1] = dec_ca_wv + o;
            A.p[40 + i] = dec_ca_wq + o;
            A.p[44 + i] = dec_ca_wo + o;
        }
        repack_attn<<<dim3(16, 16, 48), blk, 0, stream>>>(A, wa);
        FfPtrs F;
        for (int i = 0; i < 4; ++i) {
            F.p[0 + i]  = enc_ff1_w + (size_t)i * 1048576;
            F.p[4 + i]  = dec_ff1_w + (size_t)i * 1048576;
            F.p[8 + i]  = enc_ff2_w + (size_t)i * 1048576;
            F.p[12 + i] = dec_ff2_w + (size_t)i * 1048576;
        }
        repack_ff<<<dim3(1024, 16), blk, 0, stream>>>(F, wf);
    }

    auto mkd = [&](const ushort* A, int lda, const ushort* Bt, int ldb,
                   ushort* C, int ldc, int N, int K,
                   const float* bias, int relu, ushort* VT, int vcol0) {
        GDesc d; d.A = A; d.lda = lda; d.Bt = Bt; d.ldb = ldb;
        d.C = C; d.ldc = ldc; d.N = N; d.K = K;
        d.bias = bias; d.relu = relu; d.VT = VT; d.vcol0 = vcol0;
        return d;
    };
    auto g128 = [&](const GDesc& d) {
        gemm_one<128><<<dim3(d.N / 128, ROWS / 128), blk, 0, stream>>>(d);
    };
    auto g64 = [&](const GDesc& d) {
        gemm_one<64><<<dim3(d.N / 64, ROWS / 128), blk, 0, stream>>>(d);
    };

    /* input projections (1 launch) */
    input_proj2<<<dim3(ROWS * D_MODEL / 256, 2), blk, 0, stream>>>(
        src, src_lin_w, src_lin_b, src_pos, enc_x32, enc_xb, 16,
        tgt, tgt_lin_w, tgt_lin_b, tgt_pos, dec_x32, dec_xb, 8);

    /* ===================== encoder ===================== */
    for (int i = 0; i < 4; ++i) {
        g128(mkd(enc_xb, 512, wa + (size_t)(i * 3) * 262144, 512, qkvb, 1536,
                 1536, 512, nullptr, 0, vt, 1024));
        flash_attn<<<dim3(8, 64), blk, 0, stream>>>(qkvb, 1536, qkvb + 512, 1536, vt,
                                                    ctxb, D_MODEL, SEQ);
        g64(mkd(ctxb, 512, wa + (size_t)(12 + i) * 262144, 512, attnb, 512,
                512, 512, nullptr, 0, nullptr, 0));
        add_ln<<<ROWS, blk, 0, stream>>>(attnb, enc_x32, enc_ln1_g + i * 512,
                                         enc_ln1_b + i * 512, enc_x32, enc_xb);
        g128(mkd(enc_xb, 512, wf + (size_t)i * 1048576, 512, ffhb, 2048,
                 2048, 512, enc_ff1_b + i * 2048, 1, nullptr, 0));
        g64(mkd(ffhb, 2048, wf + (size_t)(8 + i) * 1048576, 2048, attnb, 512,
                512, 2048, enc_ff2_b + i * 512, 0, nullptr, 0));
        add_ln<<<ROWS, blk, 0, stream>>>(attnb, enc_x32, enc_ln2_g + i * 512,
                                         enc_ln2_b + i * 512, enc_x32, enc_xb);
    }

    /* ===================== decoder ===================== */
    for (int i = 0; i < 4; ++i) {
        /* masked self-attention */
        g128(mkd(dec_xb, 512, wa + (size_t)(16 + i * 3) * 262144, 512, qkvb, 1536,
                 1536, 512, nullptr, 0, vt, 1024));
        flash_attn<<<dim3(8, 64), blk, 0, stream>>>(qkvb, 1536, qkvb + 512, 1536, vt,
                                                    ctxb, D_MODEL, KLEN_MASKED);
        g64(mkd(ctxb, 512, wa + (size_t)(28 + i) * 262144, 512, attnb, 512,
                512, 512, nullptr, 0, nullptr, 0));
        add_ln<<<ROWS, blk, 0, stream>>>(attnb, dec_x32, dec_ln1_g + i * 512,
                                         dec_ln1_b + i * 512, dec_x32, dec_xb);
        /* cross-attention: q-proj (dec_x) and kv-proj (enc_x) in ONE launch */
        {
            GDesc dq = mkd(dec_xb, 512, wa + (size_t)(40 + i) * 262144, 512, qb, 512,
                           512, 512, nullptr, 0, nullptr, 0);
            GDesc dkv = mkd(enc_xb, 512, wa + (size_t)(32 + i * 2) * 262144, 512, kvb, 1024,
                            1024, 512, nullptr, 0, vt, 512);
            gemm_two<<<dim3(8, ROWS / 128, 2), blk, 0, stream>>>(dq, dkv);
        }
        flash_attn<<<dim3(8, 64), blk, 0, stream>>>(qb, 512, kvb, 1024, vt,
                                                    ctxb, D_MODEL, SEQ);
        g64(mkd(ctxb, 512, wa + (size_t)(44 + i) * 262144, 512, attnb, 512,
                512, 512, nullptr, 0, nullptr, 0));
        add_ln<<<ROWS, blk, 0, stream>>>(attnb, dec_x32, dec_ln2_g + i * 512,
                                         dec_ln2_b + i * 512, dec_x32, dec_xb);
        /* feed-forward */
        g128(mkd(dec_xb, 512, wf + (size_t)(4 + i) * 1048576, 512, ffhb, 2048,
                 2048, 512, dec_ff1_b + i * 2048, 1, nullptr, 0));
        g64(mkd(ffhb, 2048, wf + (size_t)(12 + i) * 1048576, 2048, attnb, 512,
                512, 2048, dec_ff2_b + i * 512, 0, nullptr, 0));
        add_ln<<<ROWS, blk, 0, stream>>>(attnb, dec_x32, dec_ln3_g + i * 512,
                                         dec_ln3_b + i * 512, dec_x32, dec_xb);
    }

    /* final projection */
    final_proj<<<ROWS * 8 / 256, blk, 0, stream>>>(dec_x32, proj_w, proj_b, (float*)d_out);
}